// Round 1
// baseline (442.285 us; speedup 1.0000x reference)
//
#include <hip/hip_runtime.h>

#define DI __device__ __forceinline__

typedef __attribute__((ext_vector_type(8))) short bf16x8;
typedef __attribute__((ext_vector_type(4))) float f32x4;

DI unsigned short f2bf(float x) {
  unsigned int u = __builtin_bit_cast(unsigned int, x);
  u = u + 0x7fffu + ((u >> 16) & 1u);
  return (unsigned short)(u >> 16);
}
DI float bf2f(unsigned short h) {
  unsigned int u = ((unsigned int)h) << 16;
  return __builtin_bit_cast(float, u);
}

// ---------------- K1: prep — convert X to bf16, transpose W (3x), convert E ----------
__global__ __launch_bounds__(256) void prep_kernel(
    const float* __restrict__ hs, const float* __restrict__ Wq,
    const float* __restrict__ Wk, const float* __restrict__ Wv,
    const float* __restrict__ de,
    unsigned short* __restrict__ Xb,   // [4096][768] bf16
    unsigned short* __restrict__ Wt,   // [3][768 n][768 k] bf16
    unsigned short* __restrict__ Eb)   // [2048][64] bf16 (row 2047 zero)
{
  const int bid = blockIdx.x, t = threadIdx.x;
  __shared__ unsigned short wlds[64 * 68];
  if (bid < 1536) {
    size_t base = (size_t)bid * 2048 + (size_t)t * 8;
    float4 a = *(const float4*)(hs + base);
    float4 b = *(const float4*)(hs + base + 4);
    union { unsigned short u[8]; uint4 v; } pk;
    pk.u[0]=f2bf(a.x); pk.u[1]=f2bf(a.y); pk.u[2]=f2bf(a.z); pk.u[3]=f2bf(a.w);
    pk.u[4]=f2bf(b.x); pk.u[5]=f2bf(b.y); pk.u[6]=f2bf(b.z); pk.u[7]=f2bf(b.w);
    *(uint4*)(Xb + base) = pk.v;
  } else if (bid < 1968) {
    int q = bid - 1536;
    int wi = q / 144, tile = q % 144;
    int tr = tile / 12, tc = tile % 12;
    int k0 = tr * 64, n0 = tc * 64;
    const float* W = wi == 0 ? Wq : (wi == 1 ? Wk : Wv);
    int i = t >> 2, cb = (t & 3) * 16;
    const float* src = W + (size_t)(k0 + i) * 768 + n0 + cb;
#pragma unroll
    for (int c4 = 0; c4 < 4; ++c4) {
      float4 v = *(const float4*)(src + c4 * 4);
      wlds[i * 68 + cb + c4 * 4 + 0] = f2bf(v.x);
      wlds[i * 68 + cb + c4 * 4 + 1] = f2bf(v.y);
      wlds[i * 68 + cb + c4 * 4 + 2] = f2bf(v.z);
      wlds[i * 68 + cb + c4 * 4 + 3] = f2bf(v.w);
    }
    __syncthreads();
    int n = t >> 2, ks = (t & 3) * 16;
    union { unsigned short u[16]; uint4 v[2]; } pk;
#pragma unroll
    for (int e = 0; e < 16; ++e) pk.u[e] = wlds[(ks + e) * 68 + n];
    unsigned short* dst = Wt + (size_t)wi * 589824 + (size_t)(n0 + n) * 768 + k0 + ks;
    *(uint4*)(dst) = pk.v[0];
    *(uint4*)(dst + 8) = pk.v[1];
  } else {
    int q = bid - 1968;
    size_t base = (size_t)q * 2048 + (size_t)t * 8;
    union { unsigned short u[8]; uint4 v; } pk;
    if (base < 131008) {
      float4 a = *(const float4*)(de + base);
      float4 b = *(const float4*)(de + base + 4);
      pk.u[0]=f2bf(a.x); pk.u[1]=f2bf(a.y); pk.u[2]=f2bf(a.z); pk.u[3]=f2bf(a.w);
      pk.u[4]=f2bf(b.x); pk.u[5]=f2bf(b.y); pk.u[6]=f2bf(b.z); pk.u[7]=f2bf(b.w);
    } else {
      pk.v = uint4{0u, 0u, 0u, 0u};
    }
    *(uint4*)(Eb + base) = pk.v;
  }
}

// ---------------- K2: QKV projection — 128x64 tile, BK=64, bf16 MFMA -----------------
__global__ __launch_bounds__(256) void proj_kernel(
    const unsigned short* __restrict__ Xb, const unsigned short* __restrict__ Wt,
    const float* __restrict__ bq, const float* __restrict__ bk, const float* __restrict__ bv,
    unsigned short* __restrict__ Qb, unsigned short* __restrict__ Kb,
    unsigned short* __restrict__ Vb)
{
  const int x = blockIdx.x, y = blockIdx.y, z = blockIdx.z;
  const int t = threadIdx.x, w = t >> 6, lane = t & 63, g = lane >> 4, ln = lane & 15;
  __shared__ __align__(16) unsigned char smem[24576];
  unsigned char* sX = smem;          // [128][128B] swizzled
  unsigned char* sW = smem + 16384;  // [64][128B]  swizzled
  const float* bias = z == 0 ? bq : (z == 1 ? bk : bv);
  const unsigned short* W = Wt + (size_t)z * 589824;
  unsigned short* Out = z == 0 ? Qb : (z == 1 ? Kb : Vb);
  const int m0 = x * 128, n0 = y * 64;

  f32x4 acc[2][4];
#pragma unroll
  for (int a = 0; a < 2; ++a)
#pragma unroll
    for (int c = 0; c < 4; ++c) acc[a][c] = f32x4{0.f, 0.f, 0.f, 0.f};

  uint4 xr[4], wr[2];
#pragma unroll
  for (int i = 0; i < 4; ++i) {
    int p = i * 4096 + t * 16, row = p >> 7, col = p & 127;
    xr[i] = *(const uint4*)((const unsigned char*)Xb + (size_t)(m0 + row) * 1536 + col);
  }
#pragma unroll
  for (int i = 0; i < 2; ++i) {
    int p = i * 4096 + t * 16, row = p >> 7, col = p & 127;
    wr[i] = *(const uint4*)((const unsigned char*)W + (size_t)(n0 + row) * 1536 + col);
  }
  for (int kt = 0; kt < 12; ++kt) {
    __syncthreads();
#pragma unroll
    for (int i = 0; i < 4; ++i) {
      int p = i * 4096 + t * 16, row = p >> 7;
      *(uint4*)(sX + (p ^ ((row & 7) << 4))) = xr[i];
    }
#pragma unroll
    for (int i = 0; i < 2; ++i) {
      int p = i * 4096 + t * 16, row = p >> 7;
      *(uint4*)(sW + (p ^ ((row & 7) << 4))) = wr[i];
    }
    if (kt < 11) {
      int kb2 = (kt + 1) * 128;
#pragma unroll
      for (int i = 0; i < 4; ++i) {
        int p = i * 4096 + t * 16, row = p >> 7, col = p & 127;
        xr[i] = *(const uint4*)((const unsigned char*)Xb + (size_t)(m0 + row) * 1536 + kb2 + col);
      }
#pragma unroll
      for (int i = 0; i < 2; ++i) {
        int p = i * 4096 + t * 16, row = p >> 7, col = p & 127;
        wr[i] = *(const uint4*)((const unsigned char*)W + (size_t)(n0 + row) * 1536 + kb2 + col);
      }
    }
    __syncthreads();
    bf16x8 af[2][2], bfr[4][2];
#pragma unroll
    for (int ms = 0; ms < 2; ++ms)
#pragma unroll
      for (int ks = 0; ks < 2; ++ks) {
        int row = w * 32 + ms * 16 + ln;
        int ad = (row * 128 + ks * 64 + g * 16) ^ ((row & 7) << 4);
        af[ms][ks] = *(const bf16x8*)(sX + ad);
      }
#pragma unroll
    for (int c = 0; c < 4; ++c)
#pragma unroll
      for (int ks = 0; ks < 2; ++ks) {
        int row = c * 16 + ln;
        int ad = (row * 128 + ks * 64 + g * 16) ^ ((row & 7) << 4);
        bfr[c][ks] = *(const bf16x8*)(sW + ad);
      }
#pragma unroll
    for (int ms = 0; ms < 2; ++ms)
#pragma unroll
      for (int c = 0; c < 4; ++c) {
        acc[ms][c] = __builtin_amdgcn_mfma_f32_16x16x32_bf16(af[ms][0], bfr[c][0], acc[ms][c], 0, 0, 0);
        acc[ms][c] = __builtin_amdgcn_mfma_f32_16x16x32_bf16(af[ms][1], bfr[c][1], acc[ms][c], 0, 0, 0);
      }
  }
  float b4[4];
#pragma unroll
  for (int c = 0; c < 4; ++c) b4[c] = bias[n0 + c * 16 + ln];
#pragma unroll
  for (int ms = 0; ms < 2; ++ms)
#pragma unroll
    for (int c = 0; c < 4; ++c)
#pragma unroll
      for (int jj = 0; jj < 4; ++jj) {
        int m = m0 + w * 32 + ms * 16 + g * 4 + jj;
        int bb = m >> 10, s = m & 1023;
        float v = acc[ms][c][jj] + b4[c];
        Out[((size_t)(bb * 12 + y) * 1024 + s) * 64 + c * 16 + ln] = f2bf(v);
      }
}

// ---------------- K3: V -> V^T  ([bh][s][d] -> [bh][d][s]) ---------------------------
__global__ __launch_bounds__(256) void vtrans_kernel(
    const unsigned short* __restrict__ Vb, unsigned short* __restrict__ Vtb)
{
  const int s0 = blockIdx.x * 256, bh = blockIdx.y, t = threadIdx.x;
  __shared__ __align__(16) unsigned short lds[256 * 64];
  const unsigned short* src = Vb + ((size_t)bh * 1024 + s0 + t) * 64;
#pragma unroll
  for (int gi = 0; gi < 8; ++gi) {
    uint4 v = *(const uint4*)(src + gi * 8);
    *(uint4*)((unsigned char*)lds + t * 128 + ((gi ^ (t & 7)) << 4)) = v;
  }
  __syncthreads();
  const int d = t >> 2, seg = t & 3;
  unsigned short* dst = Vtb + ((size_t)bh * 64 + d) * 1024 + s0 + seg * 64;
#pragma unroll
  for (int ck = 0; ck < 8; ++ck) {
    union { unsigned short u[8]; uint4 v; } pk;
#pragma unroll
    for (int e = 0; e < 8; ++e) {
      int sl = seg * 64 + ck * 8 + e;
      pk.u[e] = lds[sl * 64 + (((d >> 3) ^ (sl & 7)) << 3) + (d & 7)];
    }
    *(uint4*)(dst + ck * 8) = pk.v;
  }
}

// ---------------- K4: fused attention with relative bias + mask-multiplied softmax ---
__global__ __launch_bounds__(256) void attn_kernel(
    const float* __restrict__ amask, const float* __restrict__ rmask,
    const unsigned short* __restrict__ Qb, const unsigned short* __restrict__ Kb,
    const unsigned short* __restrict__ Vtb, const unsigned short* __restrict__ Eb,
    float* __restrict__ out)
{
  const int h = blockIdx.x, lb = blockIdx.y, b = blockIdx.z;
  const int bh = b * 12 + h, l0 = lb * 64;
  const int t = threadIdx.x, w = t >> 6, lane = t & 63, g = lane >> 4, ln = lane & 15;
  __shared__ __align__(16) unsigned char smem[59392];
  unsigned char* sK = smem;                              // [64 r][64 k] swz
  unsigned char* sV = smem + 8192;                       // [64 d][64 r] swz
  unsigned char* sP = smem + 16384;                      // [64 l][64 r] swz
  unsigned short* Gt = (unsigned short*)(smem + 24576);  // [128 j][68] cols=l
  unsigned short* Ht = (unsigned short*)(smem + 41984);  // [128 j][68] cols=r

  const unsigned short* Qrow = Qb + ((size_t)bh * 1024 + l0 + w * 16 + ln) * 64;
  const bf16x8 qa0 = *(const bf16x8*)(Qrow + g * 8);
  const bf16x8 qa1 = *(const bf16x8*)(Qrow + 32 + g * 8);

  f32x4 ctx[4];
#pragma unroll
  for (int c = 0; c < 4; ++c) ctx[c] = f32x4{0.f, 0.f, 0.f, 0.f};
  float mrun[4] = {-1e30f, -1e30f, -1e30f, -1e30f};
  float sig[4] = {0.f, 0.f, 0.f, 0.f};

  const unsigned char* Kbase = (const unsigned char*)(Kb + (size_t)bh * 65536);
  const unsigned char* Vbase = (const unsigned char*)(Vtb + (size_t)bh * 65536);

  uint4 kp[2], vp[2];
#pragma unroll
  for (int i = 0; i < 2; ++i) {
    int p = i * 4096 + t * 16, row = p >> 7, col = p & 127;
    kp[i] = *(const uint4*)(Kbase + (size_t)row * 128 + col);
    vp[i] = *(const uint4*)(Vbase + (size_t)row * 2048 + col);
  }

  for (int it = 0; it < 16; ++it) {
    const int r0 = it * 64;
    __syncthreads();
#pragma unroll
    for (int i = 0; i < 2; ++i) {
      int p = i * 4096 + t * 16, row = p >> 7;
      int ad = p ^ ((row & 7) << 4);
      *(uint4*)(sK + ad) = kp[i];
      *(uint4*)(sV + ad) = vp[i];
    }
    if (it < 15) {
      int r1 = r0 + 64;
#pragma unroll
      for (int i = 0; i < 2; ++i) {
        int p = i * 4096 + t * 16, row = p >> 7, col = p & 127;
        kp[i] = *(const uint4*)(Kbase + (size_t)(r1 + row) * 128 + col);
        vp[i] = *(const uint4*)(Vbase + (size_t)row * 2048 + r1 * 2 + col);
      }
    }
    // ---- G phase: G[l][j] = q[l] . E[D0+j]  (only j-window this wave gathers)
    const int D0 = l0 - r0 + 960;
#pragma unroll
    for (int cc = 0; cc < 5; ++cc) {
      int c = w + cc;
      const unsigned short* Erow = Eb + (size_t)(D0 + c * 16 + ln) * 64;
      bf16x8 e0 = *(const bf16x8*)(Erow + g * 8);
      bf16x8 e1 = *(const bf16x8*)(Erow + 32 + g * 8);
      f32x4 ga = f32x4{0.f, 0.f, 0.f, 0.f};
      ga = __builtin_amdgcn_mfma_f32_16x16x32_bf16(qa0, e0, ga, 0, 0, 0);
      ga = __builtin_amdgcn_mfma_f32_16x16x32_bf16(qa1, e1, ga, 0, 0, 0);
      ushort4 pk = {f2bf(ga[0]), f2bf(ga[1]), f2bf(ga[2]), f2bf(ga[3])};
      *(ushort4*)(Gt + (size_t)(c * 16 + ln) * 68 + w * 16 + g * 4) = pk;
    }
    __syncthreads();  // staging visible
    bf16x8 kb[4][2];
#pragma unroll
    for (int c = 0; c < 4; ++c)
#pragma unroll
      for (int ks = 0; ks < 2; ++ks) {
        int row = c * 16 + ln;
        int ad = (row * 128 + ks * 64 + g * 16) ^ ((row & 7) << 4);
        kb[c][ks] = *(const bf16x8*)(sK + ad);
      }
    bf16x8 ha0, ha1;
    {
      int row = w * 16 + ln;
      ha0 = *(const bf16x8*)(sK + ((row * 128 + g * 16) ^ ((row & 7) << 4)));
      ha1 = *(const bf16x8*)(sK + ((row * 128 + 64 + g * 16) ^ ((row & 7) << 4)));
    }
    // ---- H phase: H[r][j] = k[r] . E[D0+j]
#pragma unroll
    for (int c = 0; c < 8; ++c) {
      const unsigned short* Erow = Eb + (size_t)(D0 + c * 16 + ln) * 64;
      bf16x8 e0 = *(const bf16x8*)(Erow + g * 8);
      bf16x8 e1 = *(const bf16x8*)(Erow + 32 + g * 8);
      f32x4 hac = f32x4{0.f, 0.f, 0.f, 0.f};
      hac = __builtin_amdgcn_mfma_f32_16x16x32_bf16(ha0, e0, hac, 0, 0, 0);
      hac = __builtin_amdgcn_mfma_f32_16x16x32_bf16(ha1, e1, hac, 0, 0, 0);
      ushort4 pk = {f2bf(hac[0]), f2bf(hac[1]), f2bf(hac[2]), f2bf(hac[3])};
      *(ushort4*)(Ht + (size_t)(c * 16 + ln) * 68 + w * 16 + g * 4) = pk;
    }
    __syncthreads();  // Ht visible to all waves
    // ---- bias gather into C, then QK^T MFMAs accumulate
    f32x4 sacc[4];
#pragma unroll
    for (int ct = 0; ct < 4; ++ct) {
      int rlb = ct * 16 + ln;
      f32x4 si;
#pragma unroll
      for (int jj = 0; jj < 4; ++jj) {
        int llb = w * 16 + g * 4 + jj;
        int j = llb - rlb + 63;
        si[jj] = bf2f(Gt[(size_t)j * 68 + llb]) + bf2f(Ht[(size_t)j * 68 + rlb]);
      }
      sacc[ct] = si;
      sacc[ct] = __builtin_amdgcn_mfma_f32_16x16x32_bf16(qa0, kb[ct][0], sacc[ct], 0, 0, 0);
      sacc[ct] = __builtin_amdgcn_mfma_f32_16x16x32_bf16(qa1, kb[ct][1], sacc[ct], 0, 0, 0);
    }
    // ---- online softmax with multiplicative mask (no log)
    float sv[4][4], am4[4];
#pragma unroll
    for (int ct = 0; ct < 4; ++ct) am4[ct] = amask[b * 1024 + r0 + ct * 16 + ln];
    float rmax[4];
#pragma unroll
    for (int jj = 0; jj < 4; ++jj) {
#pragma unroll
      for (int ct = 0; ct < 4; ++ct) sv[ct][jj] = sacc[ct][jj] * 0.125f + am4[ct];
      float rv = fmaxf(fmaxf(sv[0][jj], sv[1][jj]), fmaxf(sv[2][jj], sv[3][jj]));
#pragma unroll
      for (int mm = 1; mm < 16; mm <<= 1) rv = fmaxf(rv, __shfl_xor(rv, mm));
      rmax[jj] = rv;
    }
    float sf[4], mnew[4];
#pragma unroll
    for (int jj = 0; jj < 4; ++jj) {
      mnew[jj] = fmaxf(mrun[jj], rmax[jj]);
      sf[jj] = __expf(mrun[jj] - mnew[jj]);
      mrun[jj] = mnew[jj];
    }
    const float* rrow = rmask + (size_t)b * 1048576 + (size_t)(l0 + w * 16 + g * 4) * 1024 + r0;
    float rs[4] = {0.f, 0.f, 0.f, 0.f};
    unsigned short pb[4][4];
#pragma unroll
    for (int ct = 0; ct < 4; ++ct)
#pragma unroll
      for (int jj = 0; jj < 4; ++jj) {
        float mv = rrow[(size_t)jj * 1024 + ct * 16 + ln];
        mv = fmaxf(mv, 1e-5f);
        float p = mv * __expf(sv[ct][jj] - mnew[jj]);
        rs[jj] += p;
        pb[ct][jj] = f2bf(p);
      }
#pragma unroll
    for (int jj = 0; jj < 4; ++jj) {
      float rv = rs[jj];
#pragma unroll
      for (int mm = 1; mm < 16; mm <<= 1) rv += __shfl_xor(rv, mm);
      sig[jj] = sig[jj] * sf[jj] + rv;
    }
#pragma unroll
    for (int c = 0; c < 4; ++c)
#pragma unroll
      for (int jj = 0; jj < 4; ++jj) ctx[c][jj] *= sf[jj];
    // ---- P -> LDS (wave-private rows), then PV
#pragma unroll
    for (int ct = 0; ct < 4; ++ct)
#pragma unroll
      for (int jj = 0; jj < 4; ++jj) {
        int row = w * 16 + g * 4 + jj;
        int ad = (row * 128 + (ct * 16 + ln) * 2) ^ ((row & 7) << 4);
        *(unsigned short*)(sP + ad) = pb[ct][jj];
      }
    bf16x8 pa0, pa1;
    {
      int row = w * 16 + ln;
      pa0 = *(const bf16x8*)(sP + ((row * 128 + g * 16) ^ ((row & 7) << 4)));
      pa1 = *(const bf16x8*)(sP + ((row * 128 + 64 + g * 16) ^ ((row & 7) << 4)));
    }
#pragma unroll
    for (int cd = 0; cd < 4; ++cd) {
      int row = cd * 16 + ln;
      bf16x8 v0 = *(const bf16x8*)(sV + ((row * 128 + g * 16) ^ ((row & 7) << 4)));
      bf16x8 v1 = *(const bf16x8*)(sV + ((row * 128 + 64 + g * 16) ^ ((row & 7) << 4)));
      ctx[cd] = __builtin_amdgcn_mfma_f32_16x16x32_bf16(pa0, v0, ctx[cd], 0, 0, 0);
      ctx[cd] = __builtin_amdgcn_mfma_f32_16x16x32_bf16(pa1, v1, ctx[cd], 0, 0, 0);
    }
  }
#pragma unroll
  for (int cd = 0; cd < 4; ++cd)
#pragma unroll
    for (int jj = 0; jj < 4; ++jj) {
      int l = l0 + w * 16 + g * 4 + jj;
      out[((size_t)b * 1024 + l) * 768 + h * 64 + cd * 16 + ln] = ctx[cd][jj] / sig[jj];
    }
}

extern "C" void kernel_launch(void* const* d_in, const int* in_sizes, int n_in,
                              void* d_out, int out_size, void* d_ws, size_t ws_size,
                              hipStream_t stream) {
  const float* hs    = (const float*)d_in[0];
  const float* amask = (const float*)d_in[1];
  const float* rmask = (const float*)d_in[2];
  const float* Wq    = (const float*)d_in[3];
  const float* bq    = (const float*)d_in[4];
  const float* Wk    = (const float*)d_in[5];
  const float* bk    = (const float*)d_in[6];
  const float* Wv    = (const float*)d_in[7];
  const float* bv    = (const float*)d_in[8];
  const float* de    = (const float*)d_in[9];
  unsigned char* ws = (unsigned char*)d_ws;
  unsigned short* Xb  = (unsigned short*)(ws + 0);         // 6291456 B
  unsigned short* Wt  = (unsigned short*)(ws + 6291456);   // 3538944 B
  unsigned short* Eb  = (unsigned short*)(ws + 9830400);   // 262144 B
  unsigned short* Qb  = (unsigned short*)(ws + 10092544);  // 6291456 B
  unsigned short* Kb  = (unsigned short*)(ws + 16384000);  // 6291456 B
  unsigned short* Vb  = (unsigned short*)(ws + 22675456);  // 6291456 B
  unsigned short* Vtb = (unsigned short*)(ws + 28966912);  // 6291456 B
  float* out = (float*)d_out;

  hipLaunchKernelGGL(prep_kernel, dim3(2032), dim3(256), 0, stream,
                     hs, Wq, Wk, Wv, de, Xb, Wt, Eb);
  hipLaunchKernelGGL(proj_kernel, dim3(32, 12, 3), dim3(256), 0, stream,
                     Xb, Wt, bq, bk, bv, Qb, Kb, Vb);
  hipLaunchKernelGGL(vtrans_kernel, dim3(4, 48), dim3(256), 0, stream, Vb, Vtb);
  hipLaunchKernelGGL(attn_kernel, dim3(12, 16, 4), dim3(256), 0, stream,
                     amask, rmask, Qb, Kb, Vtb, Eb, out);
}